// Round 21
// baseline (301.746 us; speedup 1.0000x reference)
//
#include <hip/hip_runtime.h>
#include <math.h>

typedef float f32x4 __attribute__((ext_vector_type(4)));
typedef short s16x8 __attribute__((ext_vector_type(8)));

#define DIM_ 768
#define HEADS_ 12
#define DH_ 64
#define HID_ 3072
#define SEQ_ 1024
#define BATCH_ 8
#define ROWS_ (BATCH_*SEQ_)   // 8192

static __device__ __forceinline__ ushort f2bf(float f) {
    union { float f; unsigned u; } v; v.f = f;
    unsigned r = (v.u + 0x7fffu + ((v.u >> 16) & 1u)) >> 16;
    return (ushort)r;
}
static __device__ __forceinline__ float bf2f(ushort u) {
    union { unsigned u; float f; } v; v.u = ((unsigned)u) << 16;
    return v.f;
}

static __device__ __forceinline__ void glds16(const ushort* gp, ushort* lp) {
    __builtin_amdgcn_global_load_lds(
        (const __attribute__((address_space(1))) void*)gp,
        (__attribute__((address_space(3))) void*)lp, 16, 0, 0);
}

// ---------------- prep: cast x to bf16 ----------------
__global__ __launch_bounds__(256) void cast_bf16_kernel(
    const float* __restrict__ in, ushort* __restrict__ out, int n4)
{
    int i = blockIdx.x * 256 + threadIdx.x;
    if (i >= n4) return;
    float4 v = ((const float4*)in)[i];
    ushort4 o;
    o.x = f2bf(v.x); o.y = f2bf(v.y); o.z = f2bf(v.z); o.w = f2bf(v.w);
    ((ushort4*)out)[i] = o;
}

// ---------------- prep: transpose+cast W[K][N] -> WT[N][K] bf16 ----------------
__global__ __launch_bounds__(256) void transpose_cast_kernel(
    const float* __restrict__ W, ushort* __restrict__ WT, int K, int N)
{
    __shared__ float tile[32][33];
    int n0 = blockIdx.x * 32, k0 = blockIdx.y * 32;
    int tx = threadIdx.x, ty = threadIdx.y; // 32 x 8
#pragma unroll
    for (int i = 0; i < 4; i++)
        tile[ty + i * 8][tx] = W[(size_t)(k0 + ty + i * 8) * N + n0 + tx];
    __syncthreads();
#pragma unroll
    for (int i = 0; i < 4; i++)
        WT[(size_t)(n0 + ty + i * 8) * K + k0 + tx] = f2bf(tile[tx][ty + i * 8]);
}

// ---- Wqkv transpose with column permutation (R16-validated) ----
__global__ __launch_bounds__(256) void transpose_cast_qkv_kernel(
    const float* __restrict__ W, ushort* __restrict__ WT)
{
    __shared__ float tile[32][33];
    int n0 = blockIdx.x * 32, k0 = blockIdx.y * 32;
    int tx = threadIdx.x, ty = threadIdx.y; // 32 x 8
    int np = n0 + tx;
    int part = np / 768, idx = np % 768;
    int oc = ((idx >> 6) * 192) + ((idx & 63) * 3) + part;
#pragma unroll
    for (int i = 0; i < 4; i++)
        tile[ty + i * 8][tx] = W[(size_t)(k0 + ty + i * 8) * 2304 + oc];
    __syncthreads();
#pragma unroll
    for (int i = 0; i < 4; i++)
        WT[(size_t)(n0 + ty + i * 8) * 768 + k0 + tx] = f2bf(tile[tx][ty + i * 8]);
}

// ---- V transpose: vb[bh][1024][64] -> vT[bh][64][1024] ----
__global__ __launch_bounds__(256) void v_transpose_kernel(
    const ushort* __restrict__ vb, ushort* __restrict__ vT)
{
    __shared__ ushort tile[32][33];
    int dh0 = blockIdx.x * 32;
    int sq0 = blockIdx.y * 32;
    int bh  = blockIdx.z;
    int tx = threadIdx.x, ty = threadIdx.y; // 32 x 8
    const ushort* src = vb + (size_t)bh * SEQ_ * DH_;
    ushort* dst = vT + (size_t)bh * DH_ * SEQ_;
#pragma unroll
    for (int i = 0; i < 4; i++)
        tile[ty + i * 8][tx] = src[(size_t)(sq0 + ty + i * 8) * DH_ + dh0 + tx];
    __syncthreads();
#pragma unroll
    for (int i = 0; i < 4; i++)
        dst[(size_t)(dh0 + ty + i * 8) * SEQ_ + sq0 + tx] = tile[tx][ty + i * 8];
}

// ---------------- 128^2 GEMM (R16/R20-validated) for QKV and proj ----------------
#define EPI_PART 0
#define EPI_GELU 1
#define EPI_QKV 2

template<int EPI>
__global__ __launch_bounds__(256, 4) void gemm_bt(
    const ushort* __restrict__ A, const ushort* __restrict__ B,
    const float* __restrict__ bias,
    ushort* __restrict__ Cp,
    ushort* __restrict__ Qb, ushort* __restrict__ Kb, ushort* __restrict__ Vb,
    int M, int N, int K, int nx, int nk, int Ksl)
{
    __shared__ ushort As[128 * 64];
    __shared__ ushort Bs[128 * 64];
    const int t = threadIdx.x;
    const int lane = t & 63;
    const int w = t >> 6;
    const int wr = w >> 1, wc = w & 1;
    const int nwg = gridDim.x;
    const int chunk = nwg >> 3;
    const int lin = (blockIdx.x & 7) * chunk + (blockIdx.x >> 3);
    const int tile = lin / nk;
    const int ks = lin - tile * nk;
    const int m0 = (tile / nx) * 128, n0 = (tile % nx) * 128;
    const int lr = lane & 15, g = lane >> 4;

    const ushort* Ak = A + (size_t)ks * Ksl;
    const ushort* Bk = B + (size_t)ks * Ksl;
    const int sr = lane >> 3;
    const int scz = (((lane & 7) ^ sr)) * 8;

    f32x4 acc[4][4] = {};

    for (int k0 = 0; k0 < Ksl; k0 += 64) {
#pragma unroll
        for (int j = 0; j < 4; j++) {
            int r = w * 32 + j * 8;
            glds16(Ak + (size_t)(m0 + r + sr) * K + k0 + scz, &As[r * 64]);
            glds16(Bk + (size_t)(n0 + r + sr) * K + k0 + scz, &Bs[r * 64]);
        }
        __syncthreads();
#pragma unroll
        for (int kk = 0; kk < 2; kk++) {
            s16x8 af[4], bfr[4];
#pragma unroll
            for (int m = 0; m < 4; m++) {
                int row = wr * 64 + m * 16 + lr;
                int slot = (kk * 4 + g) ^ (row & 7);
                af[m] = *(const s16x8*)&As[row * 64 + slot * 8];
            }
#pragma unroll
            for (int n = 0; n < 4; n++) {
                int row = wc * 64 + n * 16 + lr;
                int slot = (kk * 4 + g) ^ (row & 7);
                bfr[n] = *(const s16x8*)&Bs[row * 64 + slot * 8];
            }
#pragma unroll
            for (int m = 0; m < 4; m++)
#pragma unroll
                for (int n = 0; n < 4; n++)
                    acc[m][n] = __builtin_amdgcn_mfma_f32_16x16x32_bf16(af[m], bfr[n], acc[m][n], 0, 0, 0);
        }
        __syncthreads();
    }

    ushort* Cpo = Cp ? Cp + (size_t)ks * M * N : nullptr;
    const int part = (EPI == EPI_QKV) ? (n0 / 768) : 0;
#pragma unroll
    for (int m = 0; m < 4; m++) {
        int row = m0 + wr * 64 + m * 16 + g * 4;
#pragma unroll
        for (int n = 0; n < 4; n++) {
            int col = n0 + wc * 64 + n * 16 + lr;
            float bv;
            int h = 0, dh = 0;
            if (EPI == EPI_QKV) {
                int idx = col - part * 768;
                h = idx >> 6; dh = idx & 63;
                bv = bias[h * 192 + dh * 3 + part];
            } else {
                bv = (ks == 0) ? bias[col] : 0.f;
            }
#pragma unroll
            for (int r = 0; r < 4; r++) {
                float v = acc[m][n][r] + bv;
                int rg = row + r;
                if (EPI == EPI_PART) {
                    Cpo[(size_t)rg * N + col] = f2bf(v);
                } else if (EPI == EPI_GELU) {
                    float u = v * (0.7978845608f + 0.0356774081f * v * v);
                    float th = 1.f - 2.f / (__expf(2.f * u) + 1.f);
                    Cpo[(size_t)rg * N + col] = f2bf(0.5f * v * (1.f + th));
                } else {
                    int b = rg >> 10, nrow = rg & 1023;
                    int hb = b * HEADS_ + h;
                    ushort bw = f2bf(v);
                    ushort* dst = (part == 0) ? Qb : (part == 1) ? Kb : Vb;
                    dst[((size_t)hb * SEQ_ + nrow) * DH_ + dh] = bw;
                }
            }
        }
    }
}

// ---------------- 256^2 8-phase GEMM (T2+T3+T4+T5) for W1/W2 ----------------
// 8 waves (2x4), BK=64, 128KB LDS: [dbuf][half(128 rows)] for A and B.
// Per phase: stage 1 half-tile (2 glds16) -> counted vmcnt at K-tile starts
// -> barrier -> ds_reads (12 at q==0 else 4) -> setprio+16 MFMA -> barrier.
// Buffer lifetimes: buf1 staged ph0-3 / consumed ph4-7; buf0 staged ph4-7 /
// consumed next-iter ph0-3; WAR separated by phase-end barriers.
template<int EPI>
__global__ __launch_bounds__(512, 1) void gemm256(
    const ushort* __restrict__ A, const ushort* __restrict__ B,
    const float* __restrict__ bias, ushort* __restrict__ Cp,
    int M, int N, int K, int nx, int nk, int Ksl)
{
    __shared__ ushort Abuf[2][2][128 * 64];
    __shared__ ushort Bbuf[2][2][128 * 64];
    const int tid = threadIdx.x;
    const int lane = tid & 63, w = tid >> 6;
    const int wm = w >> 2, wn = w & 3;
    const int lr = lane & 15, g = lane >> 4;
    const int nwg = gridDim.x, chunk = nwg >> 3;
    const int lin = (blockIdx.x & 7) * chunk + (blockIdx.x >> 3);
    const int tile = lin / nk, ks = lin - tile * nk;
    const int m0 = (tile / nx) * 256, n0 = (tile % nx) * 256;
    const ushort* Ak = A + (size_t)ks * Ksl;
    const ushort* Bk = B + (size_t)ks * Ksl;
    const int nt = Ksl >> 6;

    const int srw = lane >> 3;                  // row within 8-row band
    const int ssl = (lane & 7) ^ (lane >> 3);   // pre-swizzled source slot

    auto stageHalf = [&](int buf, int kt, int hid) {
        const ushort* src = (hid < 2) ? Ak : Bk;
        const int base = (hid < 2) ? m0 : n0;
        const int half = hid & 1;
        ushort* dst = (hid < 2) ? &Abuf[buf][half][0] : &Bbuf[buf][half][0];
#pragma unroll
        for (int j = 0; j < 2; j++) {
            int brow = (w * 2 + j) * 8;
            glds16(src + (size_t)(base + half * 128 + brow + srw) * K + kt * 64 + ssl * 8,
                   &dst[brow * 64]);
        }
    };

    f32x4 acc[8][4] = {};
    s16x8 bfr[8];

    // prologue: K-tile 0 -> buf0 (A halves then B halves)
#pragma unroll
    for (int h = 0; h < 4; h++) stageHalf(0, 0, h);

    const int niter = nt >> 1;
    for (int s = 0; s < niter; ++s) {
#pragma unroll
        for (int p = 0; p < 8; p++) {
            const int q = p & 3, bufc = p >> 2;
            const int skt = (p < 4) ? (2 * s + 1) : (2 * s + 2);
            const int sbuf = (p < 4) ? 1 : 0;
            const bool do_stage = (skt < nt);
            if (do_stage) stageHalf(sbuf, skt, q);
            if (q == 0) {
                if (do_stage) asm volatile("s_waitcnt vmcnt(2)" ::: "memory");
                else          asm volatile("s_waitcnt vmcnt(0)" ::: "memory");
            }
            __builtin_amdgcn_s_barrier();
            __builtin_amdgcn_sched_barrier(0);
            if (q == 0) {
                const ushort* bb = &Bbuf[bufc][wn >> 1][0];
                const int rl = (wn & 1) * 64;
#pragma unroll
                for (int ni = 0; ni < 4; ni++)
#pragma unroll
                    for (int kk = 0; kk < 2; kk++) {
                        int row = rl + ni * 16 + lr;
                        int slot = (kk * 4 + g) ^ (row & 7);
                        bfr[ni * 2 + kk] = *(const s16x8*)&bb[row * 64 + slot * 8];
                    }
            }
            s16x8 af[4];
            const ushort* ab = &Abuf[bufc][wm][0];
#pragma unroll
            for (int m2 = 0; m2 < 2; m2++)
#pragma unroll
                for (int kk = 0; kk < 2; kk++) {
                    int row = (2 * q + m2) * 16 + lr;
                    int slot = (kk * 4 + g) ^ (row & 7);
                    af[m2 * 2 + kk] = *(const s16x8*)&ab[row * 64 + slot * 8];
                }
            __builtin_amdgcn_s_setprio(1);
#pragma unroll
            for (int m2 = 0; m2 < 2; m2++)
#pragma unroll
                for (int ni = 0; ni < 4; ni++)
#pragma unroll
                    for (int kk = 0; kk < 2; kk++)
                        acc[2 * q + m2][ni] = __builtin_amdgcn_mfma_f32_16x16x32_bf16(
                            af[m2 * 2 + kk], bfr[ni * 2 + kk], acc[2 * q + m2][ni], 0, 0, 0);
            __builtin_amdgcn_s_setprio(0);
            __builtin_amdgcn_s_barrier();
            __builtin_amdgcn_sched_barrier(0);
        }
    }

    ushort* Cpo = Cp + (size_t)ks * M * N;
#pragma unroll
    for (int mi = 0; mi < 8; mi++) {
        int row = m0 + wm * 128 + mi * 16 + g * 4;
#pragma unroll
        for (int ni = 0; ni < 4; ni++) {
            int col = n0 + wn * 64 + ni * 16 + lr;
            float bv = (ks == 0) ? bias[col] : 0.f;
#pragma unroll
            for (int r = 0; r < 4; r++) {
                float v = acc[mi][ni][r] + bv;
                int rg = row + r;
                if (EPI == EPI_GELU) {
                    float u = v * (0.7978845608f + 0.0356774081f * v * v);
                    float th = 1.f - 2.f / (__expf(2.f * u) + 1.f);
                    Cpo[(size_t)rg * N + col] = f2bf(0.5f * v * (1.f + th));
                } else {
                    Cpo[(size_t)rg * N + col] = f2bf(v);
                }
            }
        }
    }
}

// ---- pack P (f32, post-exp) into PV A-frags via cvt_pk + permlane swaps ----
static __device__ __forceinline__ void pack_pv(
    const f32x4 (&S)[4], s16x8& pf0v, s16x8& pf1v)
{
    unsigned c[4][2];
#pragma unroll
    for (int n = 0; n < 4; n++) {
        asm("v_cvt_pk_bf16_f32 %0, %1, %2" : "=v"(c[n][0]) : "v"(S[n][0]), "v"(S[n][1]));
        asm("v_cvt_pk_bf16_f32 %0, %1, %2" : "=v"(c[n][1]) : "v"(S[n][2]), "v"(S[n][3]));
    }
    union { unsigned u[4]; s16x8 v; } pf0, pf1;
#pragma unroll
    for (int m = 0; m < 2; m++) {
        unsigned a = c[0][m], bb = c[1][m];
        asm("v_permlane32_swap_b32 %0, %1" : "+v"(a), "+v"(bb));
        asm("v_permlane16_swap_b32 %0, %1" : "+v"(a), "+v"(bb));
        pf0.u[m] = a; pf0.u[2 + m] = bb;
        unsigned a2 = c[2][m], b2 = c[3][m];
        asm("v_permlane32_swap_b32 %0, %1" : "+v"(a2), "+v"(b2));
        asm("v_permlane16_swap_b32 %0, %1" : "+v"(a2), "+v"(b2));
        pf1.u[m] = a2; pf1.u[2 + m] = b2;
    }
    pf0v = pf0.v; pf1v = pf1.v;
}

// ---------------- flash attention v9 (R13-validated): LDS-staged K/V ----------------
struct AttnState {
    s16x8 aqA0, aqA1, aqB0, aqB1;
    float lA, lB;
    f32x4 OA[4], OB[4];
};

static __device__ __forceinline__ void attn_tile_lds(
    AttnState& st, const ushort* Ksb, const ushort* Vsb, int lr, int g)
{
    const float CMAX = 20.f;
    const int x = lr & 7;
    s16x8 kf[8], vf[8];
#pragma unroll
    for (int n = 0; n < 4; n++) {
        int row = n * 16 + lr;
        kf[2 * n]     = *(const s16x8*)&Ksb[row * 64 + (g ^ x) * 8];
        kf[2 * n + 1] = *(const s16x8*)&Ksb[row * 64 + ((4 + g) ^ x) * 8];
        vf[2 * n]     = *(const s16x8*)&Vsb[row * 64 + (g ^ x) * 8];
        vf[2 * n + 1] = *(const s16x8*)&Vsb[row * 64 + ((4 + g) ^ x) * 8];
    }
    f32x4 SA[4] = {}, SB[4] = {};
#pragma unroll
    for (int n = 0; n < 4; n++) {
        SA[n] = __builtin_amdgcn_mfma_f32_16x16x32_bf16(kf[2 * n], st.aqA0, SA[n], 0, 0, 0);
        SA[n] = __builtin_amdgcn_mfma_f32_16x16x32_bf16(kf[2 * n + 1], st.aqA1, SA[n], 0, 0, 0);
    }
#pragma unroll
    for (int n = 0; n < 4; n++) {
        SB[n] = __builtin_amdgcn_mfma_f32_16x16x32_bf16(kf[2 * n], st.aqB0, SB[n], 0, 0, 0);
        SB[n] = __builtin_amdgcn_mfma_f32_16x16x32_bf16(kf[2 * n + 1], st.aqB1, SB[n], 0, 0, 0);
    }
#pragma unroll
    for (int n = 0; n < 4; n++)
#pragma unroll
        for (int r = 0; r < 4; r++) {
            SA[n][r] = __expf(SA[n][r] - CMAX);
            SB[n][r] = __expf(SB[n][r] - CMAX);
        }
    f32x4 sa = SA[0] + SA[1], sb = SB[0] + SB[1];
    sa += SA[2] + SA[3];
    sb += SB[2] + SB[3];
    st.lA += (sa[0] + sa[1]) + (sa[2] + sa[3]);
    st.lB += (sb[0] + sb[1]) + (sb[2] + sb[3]);

    s16x8 pfA0, pfA1, pfB0, pfB1;
    pack_pv(SA, pfA0, pfA1);
    pack_pv(SB, pfB0, pfB1);

#pragma unroll
    for (int n = 0; n < 4; n++) {
        st.OA[n] = __builtin_amdgcn_mfma_f32_16x16x32_bf16(pfA0, vf[2 * n], st.OA[n], 0, 0, 0);
        st.OA[n] = __builtin_amdgcn_mfma_f32_16x16x32_bf16(pfA1, vf[2 * n + 1], st.OA[n], 0, 0, 0);
    }
#pragma unroll
    for (int n = 0; n < 4; n++) {
        st.OB[n] = __builtin_amdgcn_mfma_f32_16x16x32_bf16(pfB0, vf[2 * n], st.OB[n], 0, 0, 0);
        st.OB[n] = __builtin_amdgcn_mfma_f32_16x16x32_bf16(pfB1, vf[2 * n + 1], st.OB[n], 0, 0, 0);
    }
}

__global__ __launch_bounds__(256) void attn_kernel(
    const ushort* __restrict__ Q, const ushort* __restrict__ Kb,
    const ushort* __restrict__ Vt, ushort* __restrict__ AO)
{
    __shared__ ushort Ks[2][64 * 64];
    __shared__ ushort Vs[2][64 * 64];
    const int tid = threadIdx.x, lane = tid & 63, w = tid >> 6;
    const int lr = lane & 15, g = lane >> 4;
    const int wg = blockIdx.x;
    const int lin = (wg & 7) * 96 + (wg >> 3);
    const int bh = lin >> 3;
    const int qt = lin & 7;
    const int b = bh / HEADS_, h = bh % HEADS_;
    const ushort* qh = Q + (size_t)bh * SEQ_ * DH_;
    const ushort* kh = Kb + (size_t)bh * SEQ_ * DH_;
    const ushort* vh = Vt + (size_t)bh * DH_ * SEQ_;

    const int srow = tid >> 3;
    const int ss = (tid & 7) ^ (srow & 7);

    AttnState st;
    const int qbase = qt * 128 + w * 32;
    st.aqA0 = *(const s16x8*)(qh + (size_t)(qbase + lr) * DH_ + g * 8);
    st.aqA1 = *(const s16x8*)(qh + (size_t)(qbase + lr) * DH_ + 32 + g * 8);
    st.aqB0 = *(const s16x8*)(qh + (size_t)(qbase + 16 + lr) * DH_ + g * 8);
    st.aqB1 = *(const s16x8*)(qh + (size_t)(qbase + 16 + lr) * DH_ + 32 + g * 8);
    st.lA = 0.f; st.lB = 0.f;
#pragma unroll
    for (int n = 0; n < 4; n++) { st.OA[n] = f32x4{}; st.OB[n] = f32x4{}; }

    auto stageK = [&](ushort* buf, int kbase) {
        glds16(kh + (size_t)(kbase + srow) * DH_ + ss * 8, &buf[tid * 8]);
        glds16(kh + (size_t)(kbase + 32 + srow) * DH_ + ss * 8, &buf[tid * 8 + 2048]);
    };
    auto stageV = [&](ushort* buf, int kbase) {
        glds16(vh + (size_t)srow * SEQ_ + kbase + ss * 8, &buf[tid * 8]);
        glds16(vh + (size_t)(32 + srow) * SEQ_ + kbase + ss * 8, &buf[tid * 8 + 2048]);
    };

    stageK(Ks[0], 0);
    stageV(Vs[0], 0);
    __syncthreads();

#pragma unroll 1
    for (int tkv = 0; tkv < 16; tkv += 2) {
        if (tkv + 1 < 16) { stageK(Ks[1], (tkv + 1) * 64); stageV(Vs[1], (tkv + 1) * 64); }
        attn_tile_lds(st, Ks[0], Vs[0], lr, g);
        __syncthreads();
        if (tkv + 2 < 16) { stageK(Ks[0], (tkv + 2) * 64); stageV(Vs[0], (tkv + 2) * 64); }
        attn_tile_lds(st, Ks[1], Vs[1], lr, g);
        __syncthreads();
    }

    float lA = st.lA, lB = st.lB;
    lA += __shfl_xor(lA, 16); lA += __shfl_xor(lA, 32);
    lB += __shfl_xor(lB, 16); lB += __shfl_xor(lB, 32);

    const float fin = 0.03608439182435161f;
#pragma unroll
    for (int r = 0; r < 4; r++) {
        float linvA = fin / __shfl(lA, 4 * g + r);
        float linvB = fin / __shfl(lB, 4 * g + r);
        int rowA = b * SEQ_ + qbase + 4 * g + r;
        int rowB = rowA + 16;
        ushort* aoA = AO + (size_t)rowA * DIM_ + h * DH_ + lr;
        ushort* aoB = AO + (size_t)rowB * DIM_ + h * DH_ + lr;
#pragma unroll
        for (int n = 0; n < 4; n++) {
            aoA[n * 16] = f2bf(st.OA[n][r] * linvA);
            aoB[n * 16] = f2bf(st.OB[n][r] * linvB);
        }
    }
}

// ---------------- fused residual + LayerNorm (wave per row, np partials) ----------------
__global__ __launch_bounds__(256) void ln_residual_kernel(
    const float* __restrict__ xinf, const ushort* __restrict__ xinb,
    const ushort* __restrict__ y, int np,
    const float* __restrict__ g, const float* __restrict__ be,
    float* __restrict__ outf, ushort* __restrict__ outbf, int rows)
{
    int w = threadIdx.x >> 6, lane = threadIdx.x & 63;
    int row = blockIdx.x * 4 + w;
    if (row >= rows) return;
    const size_t pstride = (size_t)ROWS_ * DIM_;
    float4 v[3];
    float s = 0.f, s2 = 0.f;
#pragma unroll
    for (int i = 0; i < 3; i++) {
        float4 a = { 0.f, 0.f, 0.f, 0.f };
        for (int j = 0; j < np; j++) {
            ushort4 u = ((const ushort4*)(y + j * pstride + (size_t)row * DIM_))[i * 64 + lane];
            a.x += bf2f(u.x); a.y += bf2f(u.y); a.z += bf2f(u.z); a.w += bf2f(u.w);
        }
        v[i] = a;
        s += (a.x + a.y) + (a.z + a.w);
        s2 += (a.x * a.x + a.y * a.y) + (a.z * a.z + a.w * a.w);
    }
#pragma unroll
    for (int o = 1; o < 64; o <<= 1) { s += __shfl_xor(s, o); s2 += __shfl_xor(s2, o); }
    float mu = s * (1.f / 768.f);
    float var = s2 * (1.f / 768.f) - mu * mu;
    float rs = rsqrtf(var + 1e-5f);
    const float4* xr = xinf ? (const float4*)(xinf + (size_t)row * DIM_) : nullptr;
    const ushort4* xb = xinb ? (const ushort4*)(xinb + (size_t)row * DIM_) : nullptr;
    const float4* g4 = (const float4*)g;
    const float4* b4 = (const float4*)be;
    float4* of = outf ? (float4*)(outf + (size_t)row * DIM_) : nullptr;
#pragma unroll
    for (int i = 0; i < 3; i++) {
        int c = i * 64 + lane;
        float4 gg = g4[c], bb = b4[c];
        float4 xx;
        if (xr) xx = xr[c];
        else {
            ushort4 u = xb[c];
            xx = { bf2f(u.x), bf2f(u.y), bf2f(u.z), bf2f(u.w) };
        }
        float4 o;
        o.x = xx.x + (v[i].x - mu) * rs * gg.x + bb.x;
        o.y = xx.y + (v[i].y - mu) * rs * gg.y + bb.y;
        o.z = xx.z + (v[i].z - mu) * rs * gg.z + bb.z;
        o.w = xx.w + (v[i].w - mu) * rs * gg.w + bb.w;
        if (of) of[c] = o;
        if (outbf) {
            ushort4 ob;
            ob.x = f2bf(o.x); ob.y = f2bf(o.y); ob.z = f2bf(o.z); ob.w = f2bf(o.w);
            ((ushort4*)(outbf + (size_t)row * DIM_))[c] = ob;
        }
    }
}

// ---------------- launch ----------------
extern "C" void kernel_launch(void* const* d_in, const int* in_sizes, int n_in,
                              void* d_out, int out_size, void* d_ws, size_t ws_size,
                              hipStream_t stream)
{
    const float* x    = (const float*)d_in[0];
    const float* Wqkv = (const float*)d_in[1];
    const float* bqkv = (const float*)d_in[2];
    const float* Wproj= (const float*)d_in[3];
    const float* bproj= (const float*)d_in[4];
    const float* W1   = (const float*)d_in[5];
    const float* b1   = (const float*)d_in[6];
    const float* W2   = (const float*)d_in[7];
    const float* b2   = (const float*)d_in[8];
    const float* g1   = (const float*)d_in[9];
    const float* be1  = (const float*)d_in[10];
    const float* g2   = (const float*)d_in[11];
    const float* be2  = (const float*)d_in[12];
    float* out = (float*)d_out;

    char* ws = (char*)d_ws;
    size_t off = 0;
    auto alloc = [&](size_t bytes) -> void* {
        void* p = ws + off;
        off += (bytes + 255) & ~(size_t)255;
        return p;
    };
    ushort* wqkvT  = (ushort*)alloc((size_t)2304 * 768 * 2);
    ushort* wprojT = (ushort*)alloc((size_t)768 * 768 * 2);
    ushort* w1T    = (ushort*)alloc((size_t)3072 * 768 * 2);
    ushort* w2T    = (ushort*)alloc((size_t)768 * 3072 * 2);
    ushort* xbf    = (ushort*)alloc((size_t)ROWS_ * DIM_ * 2);
    ushort* qb     = (ushort*)alloc((size_t)ROWS_ * DIM_ * 2);
    ushort* kb     = (ushort*)alloc((size_t)ROWS_ * DIM_ * 2);
    ushort* vb     = (ushort*)alloc((size_t)ROWS_ * DIM_ * 2);
    ushort* hbf    = xbf;  // alias: 4*ROWS*DIM*2 == ROWS*HID*2
    ushort* vT     = (ushort*)alloc((size_t)ROWS_ * DIM_ * 2);
    ushort* aobf   = (ushort*)alloc((size_t)ROWS_ * DIM_ * 2);
    ushort* projp  = (ushort*)alloc((size_t)4 * ROWS_ * DIM_ * 2); // up to 4 bf16 partials
    ushort* x1bf   = (ushort*)alloc((size_t)ROWS_ * DIM_ * 2);

    // prep
    cast_bf16_kernel<<<(ROWS_ * DIM_ / 4 + 255) / 256, 256, 0, stream>>>(x, xbf, ROWS_ * DIM_ / 4);
    transpose_cast_qkv_kernel<<<dim3(2304 / 32, 768 / 32), dim3(32, 8), 0, stream>>>(Wqkv, wqkvT);
    transpose_cast_kernel<<<dim3(768 / 32, 768 / 32), dim3(32, 8), 0, stream>>>(Wproj, wprojT, 768, 768);
    transpose_cast_kernel<<<dim3(3072 / 32, 768 / 32), dim3(32, 8), 0, stream>>>(W1, w1T, 768, 3072);
    transpose_cast_kernel<<<dim3(768 / 32, 3072 / 32), dim3(32, 8), 0, stream>>>(W2, w2T, 3072, 768);

    // qkv (128^2 path, validated)
    gemm_bt<EPI_QKV><<<1152, 256, 0, stream>>>(
        xbf, wqkvT, bqkv, nullptr, qb, kb, vb, ROWS_, 2304, 768, 18, 1, 768);

    v_transpose_kernel<<<dim3(2, 32, 96), dim3(32, 8), 0, stream>>>(vb, vT);

    attn_kernel<<<768, 256, 0, stream>>>(qb, kb, vT, aobf);

    // proj: 128^2 split-K x2 -> 2 bf16 partials
    gemm_bt<EPI_PART><<<768, 256, 0, stream>>>(
        aobf, wprojT, bproj, projp, nullptr, nullptr, nullptr, ROWS_, 768, 768, 6, 2, 384);

    // x1 = x + LN(sum of 2 partials)
    ln_residual_kernel<<<ROWS_ / 4, 256, 0, stream>>>(
        x, nullptr, projp, 2, g1, be1, nullptr, x1bf, ROWS_);

    // h = gelu(x1 @ W1 + b1): 256^2 8-phase (384 blocks, nx=12)
    gemm256<EPI_GELU><<<384, 512, 0, stream>>>(
        x1bf, w1T, b1, hbf, ROWS_, 3072, 768, 12, 1, 768);

    // mlp = h @ W2 + b2: 256^2 8-phase, split-K x4 (384 blocks, nx=3, Ksl=768)
    gemm256<EPI_PART><<<384, 512, 0, stream>>>(
        hbf, w2T, b2, projp, ROWS_, 768, 3072, 3, 4, 768);

    // out = x1 + LN(sum of 4 partials)
    ln_residual_kernel<<<ROWS_ / 4, 256, 0, stream>>>(
        nullptr, x1bf, projp, 4, g2, be2, out, nullptr, ROWS_);
}

// Round 22
// 240.351 us; speedup vs baseline: 1.2554x; 1.2554x over previous
//
#include <hip/hip_runtime.h>
#include <math.h>

typedef float f32x4 __attribute__((ext_vector_type(4)));
typedef short s16x8 __attribute__((ext_vector_type(8)));

#define DIM_ 768
#define HEADS_ 12
#define DH_ 64
#define HID_ 3072
#define SEQ_ 1024
#define BATCH_ 8
#define ROWS_ (BATCH_*SEQ_)   // 8192

static __device__ __forceinline__ ushort f2bf(float f) {
    union { float f; unsigned u; } v; v.f = f;
    unsigned r = (v.u + 0x7fffu + ((v.u >> 16) & 1u)) >> 16;
    return (ushort)r;
}
static __device__ __forceinline__ float bf2f(ushort u) {
    union { unsigned u; float f; } v; v.u = ((unsigned)u) << 16;
    return v.f;
}

static __device__ __forceinline__ void glds16(const ushort* gp, ushort* lp) {
    __builtin_amdgcn_global_load_lds(
        (const __attribute__((address_space(1))) void*)gp,
        (__attribute__((address_space(3))) void*)lp, 16, 0, 0);
}

// ---------------- prep: cast x to bf16 ----------------
__global__ __launch_bounds__(256) void cast_bf16_kernel(
    const float* __restrict__ in, ushort* __restrict__ out, int n4)
{
    int i = blockIdx.x * 256 + threadIdx.x;
    if (i >= n4) return;
    float4 v = ((const float4*)in)[i];
    ushort4 o;
    o.x = f2bf(v.x); o.y = f2bf(v.y); o.z = f2bf(v.z); o.w = f2bf(v.w);
    ((ushort4*)out)[i] = o;
}

// ---------------- prep: transpose+cast W[K][N] -> WT[N][K] bf16 ----------------
__global__ __launch_bounds__(256) void transpose_cast_kernel(
    const float* __restrict__ W, ushort* __restrict__ WT, int K, int N)
{
    __shared__ float tile[32][33];
    int n0 = blockIdx.x * 32, k0 = blockIdx.y * 32;
    int tx = threadIdx.x, ty = threadIdx.y; // 32 x 8
#pragma unroll
    for (int i = 0; i < 4; i++)
        tile[ty + i * 8][tx] = W[(size_t)(k0 + ty + i * 8) * N + n0 + tx];
    __syncthreads();
#pragma unroll
    for (int i = 0; i < 4; i++)
        WT[(size_t)(n0 + ty + i * 8) * K + k0 + tx] = f2bf(tile[tx][ty + i * 8]);
}

// ---- Wqkv transpose with column permutation (R16-validated) ----
__global__ __launch_bounds__(256) void transpose_cast_qkv_kernel(
    const float* __restrict__ W, ushort* __restrict__ WT)
{
    __shared__ float tile[32][33];
    int n0 = blockIdx.x * 32, k0 = blockIdx.y * 32;
    int tx = threadIdx.x, ty = threadIdx.y; // 32 x 8
    int np = n0 + tx;
    int part = np / 768, idx = np % 768;
    int oc = ((idx >> 6) * 192) + ((idx & 63) * 3) + part;
#pragma unroll
    for (int i = 0; i < 4; i++)
        tile[ty + i * 8][tx] = W[(size_t)(k0 + ty + i * 8) * 2304 + oc];
    __syncthreads();
#pragma unroll
    for (int i = 0; i < 4; i++)
        WT[(size_t)(n0 + ty + i * 8) * 768 + k0 + tx] = f2bf(tile[tx][ty + i * 8]);
}

// ---- V transpose: vb[bh][1024][64] -> vT[bh][64][1024] ----
__global__ __launch_bounds__(256) void v_transpose_kernel(
    const ushort* __restrict__ vb, ushort* __restrict__ vT)
{
    __shared__ ushort tile[32][33];
    int dh0 = blockIdx.x * 32;
    int sq0 = blockIdx.y * 32;
    int bh  = blockIdx.z;
    int tx = threadIdx.x, ty = threadIdx.y; // 32 x 8
    const ushort* src = vb + (size_t)bh * SEQ_ * DH_;
    ushort* dst = vT + (size_t)bh * DH_ * SEQ_;
#pragma unroll
    for (int i = 0; i < 4; i++)
        tile[ty + i * 8][tx] = src[(size_t)(sq0 + ty + i * 8) * DH_ + dh0 + tx];
    __syncthreads();
#pragma unroll
    for (int i = 0; i < 4; i++)
        dst[(size_t)(dh0 + ty + i * 8) * SEQ_ + sq0 + tx] = tile[tx][ty + i * 8];
}

// ---------------- GEMM: C = A @ BT^T + bias (R16/R20-validated: BK=64, XOR
// slot-swizzle, occupancy 4) ----------------
#define EPI_PART 0
#define EPI_GELU 1
#define EPI_QKV 2

template<int EPI>
__global__ __launch_bounds__(256, 4) void gemm_bt(
    const ushort* __restrict__ A, const ushort* __restrict__ B,
    const float* __restrict__ bias,
    ushort* __restrict__ Cp,
    ushort* __restrict__ Qb, ushort* __restrict__ Kb, ushort* __restrict__ Vb,
    int M, int N, int K, int nx, int nk, int Ksl)
{
    __shared__ ushort As[128 * 64];
    __shared__ ushort Bs[128 * 64];
    const int t = threadIdx.x;
    const int lane = t & 63;
    const int w = t >> 6;
    const int wr = w >> 1, wc = w & 1;
    const int nwg = gridDim.x;
    const int chunk = nwg >> 3;
    const int lin = (blockIdx.x & 7) * chunk + (blockIdx.x >> 3);
    const int tile = lin / nk;
    const int ks = lin - tile * nk;
    const int m0 = (tile / nx) * 128, n0 = (tile % nx) * 128;
    const int lr = lane & 15, g = lane >> 4;

    const ushort* Ak = A + (size_t)ks * Ksl;
    const ushort* Bk = B + (size_t)ks * Ksl;
    const int sr = lane >> 3;
    const int scz = (((lane & 7) ^ sr)) * 8;

    f32x4 acc[4][4] = {};

    for (int k0 = 0; k0 < Ksl; k0 += 64) {
#pragma unroll
        for (int j = 0; j < 4; j++) {
            int r = w * 32 + j * 8;
            glds16(Ak + (size_t)(m0 + r + sr) * K + k0 + scz, &As[r * 64]);
            glds16(Bk + (size_t)(n0 + r + sr) * K + k0 + scz, &Bs[r * 64]);
        }
        __syncthreads();
#pragma unroll
        for (int kk = 0; kk < 2; kk++) {
            s16x8 af[4], bfr[4];
#pragma unroll
            for (int m = 0; m < 4; m++) {
                int row = wr * 64 + m * 16 + lr;
                int slot = (kk * 4 + g) ^ (row & 7);
                af[m] = *(const s16x8*)&As[row * 64 + slot * 8];
            }
#pragma unroll
            for (int n = 0; n < 4; n++) {
                int row = wc * 64 + n * 16 + lr;
                int slot = (kk * 4 + g) ^ (row & 7);
                bfr[n] = *(const s16x8*)&Bs[row * 64 + slot * 8];
            }
#pragma unroll
            for (int m = 0; m < 4; m++)
#pragma unroll
                for (int n = 0; n < 4; n++)
                    acc[m][n] = __builtin_amdgcn_mfma_f32_16x16x32_bf16(af[m], bfr[n], acc[m][n], 0, 0, 0);
        }
        __syncthreads();
    }

    ushort* Cpo = Cp ? Cp + (size_t)ks * M * N : nullptr;
    const int part = (EPI == EPI_QKV) ? (n0 / 768) : 0; // block-uniform (768%128==0)
#pragma unroll
    for (int m = 0; m < 4; m++) {
        int row = m0 + wr * 64 + m * 16 + g * 4;
#pragma unroll
        for (int n = 0; n < 4; n++) {
            int col = n0 + wc * 64 + n * 16 + lr;
            float bv;
            int h = 0, dh = 0;
            if (EPI == EPI_QKV) {
                int idx = col - part * 768;
                h = idx >> 6; dh = idx & 63;
                bv = bias[h * 192 + dh * 3 + part];   // bias in original col space
            } else {
                bv = (ks == 0) ? bias[col] : 0.f;
            }
#pragma unroll
            for (int r = 0; r < 4; r++) {
                float v = acc[m][n][r] + bv;
                int rg = row + r;
                if (EPI == EPI_PART) {
                    Cpo[(size_t)rg * N + col] = f2bf(v);
                } else if (EPI == EPI_GELU) {
                    // tanh-form GELU (max |err| ~1e-3)
                    float u = v * (0.7978845608f + 0.0356774081f * v * v);
                    float th = 1.f - 2.f / (__expf(2.f * u) + 1.f);
                    float gl = 0.5f * v * (1.f + th);
                    Cpo[(size_t)rg * N + col] = f2bf(gl);
                } else { // QKV: all three parts row-major contiguous (V transposed later)
                    int b = rg >> 10, nrow = rg & 1023;
                    int hb = b * HEADS_ + h;
                    ushort bw = f2bf(v);
                    ushort* dst = (part == 0) ? Qb : (part == 1) ? Kb : Vb;
                    dst[((size_t)hb * SEQ_ + nrow) * DH_ + dh] = bw;
                }
            }
        }
    }
}

// ---- pack P (f32, post-exp) into PV A-frags via cvt_pk + permlane swaps ----
static __device__ __forceinline__ void pack_pv(
    const f32x4 (&S)[4], s16x8& pf0v, s16x8& pf1v)
{
    unsigned c[4][2];
#pragma unroll
    for (int n = 0; n < 4; n++) {
        asm("v_cvt_pk_bf16_f32 %0, %1, %2" : "=v"(c[n][0]) : "v"(S[n][0]), "v"(S[n][1]));
        asm("v_cvt_pk_bf16_f32 %0, %1, %2" : "=v"(c[n][1]) : "v"(S[n][2]), "v"(S[n][3]));
    }
    union { unsigned u[4]; s16x8 v; } pf0, pf1;
#pragma unroll
    for (int m = 0; m < 2; m++) {
        unsigned a = c[0][m], bb = c[1][m];
        asm("v_permlane32_swap_b32 %0, %1" : "+v"(a), "+v"(bb));
        asm("v_permlane16_swap_b32 %0, %1" : "+v"(a), "+v"(bb));
        pf0.u[m] = a; pf0.u[2 + m] = bb;
        unsigned a2 = c[2][m], b2 = c[3][m];
        asm("v_permlane32_swap_b32 %0, %1" : "+v"(a2), "+v"(b2));
        asm("v_permlane16_swap_b32 %0, %1" : "+v"(a2), "+v"(b2));
        pf1.u[m] = a2; pf1.u[2 + m] = b2;
    }
    pf0v = pf0.v; pf1v = pf1.v;
}

// ---------------- flash attention v9 (R13-validated): LDS-staged K/V ----------------
struct AttnState {
    s16x8 aqA0, aqA1, aqB0, aqB1;
    float lA, lB;
    f32x4 OA[4], OB[4];
};

static __device__ __forceinline__ void attn_tile_lds(
    AttnState& st, const ushort* Ksb, const ushort* Vsb, int lr, int g)
{
    const float CMAX = 20.f;
    const int x = lr & 7;
    s16x8 kf[8], vf[8];
#pragma unroll
    for (int n = 0; n < 4; n++) {
        int row = n * 16 + lr;
        kf[2 * n]     = *(const s16x8*)&Ksb[row * 64 + (g ^ x) * 8];
        kf[2 * n + 1] = *(const s16x8*)&Ksb[row * 64 + ((4 + g) ^ x) * 8];
        vf[2 * n]     = *(const s16x8*)&Vsb[row * 64 + (g ^ x) * 8];
        vf[2 * n + 1] = *(const s16x8*)&Vsb[row * 64 + ((4 + g) ^ x) * 8];
    }
    f32x4 SA[4] = {}, SB[4] = {};
#pragma unroll
    for (int n = 0; n < 4; n++) {
        SA[n] = __builtin_amdgcn_mfma_f32_16x16x32_bf16(kf[2 * n], st.aqA0, SA[n], 0, 0, 0);
        SA[n] = __builtin_amdgcn_mfma_f32_16x16x32_bf16(kf[2 * n + 1], st.aqA1, SA[n], 0, 0, 0);
    }
#pragma unroll
    for (int n = 0; n < 4; n++) {
        SB[n] = __builtin_amdgcn_mfma_f32_16x16x32_bf16(kf[2 * n], st.aqB0, SB[n], 0, 0, 0);
        SB[n] = __builtin_amdgcn_mfma_f32_16x16x32_bf16(kf[2 * n + 1], st.aqB1, SB[n], 0, 0, 0);
    }
#pragma unroll
    for (int n = 0; n < 4; n++)
#pragma unroll
        for (int r = 0; r < 4; r++) {
            SA[n][r] = __expf(SA[n][r] - CMAX);
            SB[n][r] = __expf(SB[n][r] - CMAX);
        }
    f32x4 sa = SA[0] + SA[1], sb = SB[0] + SB[1];
    sa += SA[2] + SA[3];
    sb += SB[2] + SB[3];
    st.lA += (sa[0] + sa[1]) + (sa[2] + sa[3]);
    st.lB += (sb[0] + sb[1]) + (sb[2] + sb[3]);

    s16x8 pfA0, pfA1, pfB0, pfB1;
    pack_pv(SA, pfA0, pfA1);
    pack_pv(SB, pfB0, pfB1);

#pragma unroll
    for (int n = 0; n < 4; n++) {
        st.OA[n] = __builtin_amdgcn_mfma_f32_16x16x32_bf16(pfA0, vf[2 * n], st.OA[n], 0, 0, 0);
        st.OA[n] = __builtin_amdgcn_mfma_f32_16x16x32_bf16(pfA1, vf[2 * n + 1], st.OA[n], 0, 0, 0);
    }
#pragma unroll
    for (int n = 0; n < 4; n++) {
        st.OB[n] = __builtin_amdgcn_mfma_f32_16x16x32_bf16(pfB0, vf[2 * n], st.OB[n], 0, 0, 0);
        st.OB[n] = __builtin_amdgcn_mfma_f32_16x16x32_bf16(pfB1, vf[2 * n + 1], st.OB[n], 0, 0, 0);
    }
}

__global__ __launch_bounds__(256) void attn_kernel(
    const ushort* __restrict__ Q, const ushort* __restrict__ Kb,
    const ushort* __restrict__ Vt, ushort* __restrict__ AO)
{
    __shared__ ushort Ks[2][64 * 64];
    __shared__ ushort Vs[2][64 * 64];
    const int tid = threadIdx.x, lane = tid & 63, w = tid >> 6;
    const int lr = lane & 15, g = lane >> 4;
    const int wg = blockIdx.x;                 // 0..767
    const int lin = (wg & 7) * 96 + (wg >> 3); // XCD-contiguous work id
    const int bh = lin >> 3;                   // 12 heads per XCD
    const int qt = lin & 7;
    const int b = bh / HEADS_, h = bh % HEADS_;
    const ushort* qh = Q + (size_t)bh * SEQ_ * DH_;
    const ushort* kh = Kb + (size_t)bh * SEQ_ * DH_;
    const ushort* vh = Vt + (size_t)bh * DH_ * SEQ_;

    const int srow = tid >> 3;            // 0..31
    const int ss = (tid & 7) ^ (srow & 7); // source slot (rule-21 involution)

    AttnState st;
    const int qbase = qt * 128 + w * 32;
    st.aqA0 = *(const s16x8*)(qh + (size_t)(qbase + lr) * DH_ + g * 8);
    st.aqA1 = *(const s16x8*)(qh + (size_t)(qbase + lr) * DH_ + 32 + g * 8);
    st.aqB0 = *(const s16x8*)(qh + (size_t)(qbase + 16 + lr) * DH_ + g * 8);
    st.aqB1 = *(const s16x8*)(qh + (size_t)(qbase + 16 + lr) * DH_ + 32 + g * 8);
    st.lA = 0.f; st.lB = 0.f;
#pragma unroll
    for (int n = 0; n < 4; n++) { st.OA[n] = f32x4{}; st.OB[n] = f32x4{}; }

    auto stageK = [&](ushort* buf, int kbase) {
        glds16(kh + (size_t)(kbase + srow) * DH_ + ss * 8, &buf[tid * 8]);
        glds16(kh + (size_t)(kbase + 32 + srow) * DH_ + ss * 8, &buf[tid * 8 + 2048]);
    };
    auto stageV = [&](ushort* buf, int kbase) {
        glds16(vh + (size_t)srow * SEQ_ + kbase + ss * 8, &buf[tid * 8]);
        glds16(vh + (size_t)(32 + srow) * SEQ_ + kbase + ss * 8, &buf[tid * 8 + 2048]);
    };

    stageK(Ks[0], 0);
    stageV(Vs[0], 0);
    __syncthreads();

#pragma unroll 1
    for (int tkv = 0; tkv < 16; tkv += 2) {
        if (tkv + 1 < 16) { stageK(Ks[1], (tkv + 1) * 64); stageV(Vs[1], (tkv + 1) * 64); }
        attn_tile_lds(st, Ks[0], Vs[0], lr, g);
        __syncthreads();
        if (tkv + 2 < 16) { stageK(Ks[0], (tkv + 2) * 64); stageV(Vs[0], (tkv + 2) * 64); }
        attn_tile_lds(st, Ks[1], Vs[1], lr, g);
        __syncthreads();
    }

    float lA = st.lA, lB = st.lB;
    lA += __shfl_xor(lA, 16); lA += __shfl_xor(lA, 32);
    lB += __shfl_xor(lB, 16); lB += __shfl_xor(lB, 32);

    const float fin = 0.03608439182435161f; // 1/sqrt(768), applied post-softmax
#pragma unroll
    for (int r = 0; r < 4; r++) {
        float linvA = fin / __shfl(lA, 4 * g + r);
        float linvB = fin / __shfl(lB, 4 * g + r);
        int rowA = b * SEQ_ + qbase + 4 * g + r;
        int rowB = rowA + 16;
        ushort* aoA = AO + (size_t)rowA * DIM_ + h * DH_ + lr;
        ushort* aoB = AO + (size_t)rowB * DIM_ + h * DH_ + lr;
#pragma unroll
        for (int n = 0; n < 4; n++) {
            aoA[n * 16] = f2bf(st.OA[n][r] * linvA);
            aoB[n * 16] = f2bf(st.OB[n][r] * linvB);
        }
    }
}

// ---------------- fused residual + LayerNorm (wave per row) ----------------
__global__ __launch_bounds__(256) void ln_residual_kernel(
    const float* __restrict__ xinf, const ushort* __restrict__ xinb,
    const ushort* __restrict__ y0, const ushort* __restrict__ y1,
    const float* __restrict__ g, const float* __restrict__ be,
    float* __restrict__ outf, ushort* __restrict__ outbf, int rows)
{
    int w = threadIdx.x >> 6, lane = threadIdx.x & 63;
    int row = blockIdx.x * 4 + w;
    if (row >= rows) return;
    const ushort4* y0r = (const ushort4*)(y0 + (size_t)row * DIM_);
    const ushort4* y1r = y1 ? (const ushort4*)(y1 + (size_t)row * DIM_) : nullptr;
    float4 v[3];
    float s = 0.f, s2 = 0.f;
#pragma unroll
    for (int i = 0; i < 3; i++) {
        ushort4 u0 = y0r[i * 64 + lane];
        float4 a = { bf2f(u0.x), bf2f(u0.y), bf2f(u0.z), bf2f(u0.w) };
        if (y1r) {
            ushort4 u1 = y1r[i * 64 + lane];
            a.x += bf2f(u1.x); a.y += bf2f(u1.y); a.z += bf2f(u1.z); a.w += bf2f(u1.w);
        }
        v[i] = a;
        s += (a.x + a.y) + (a.z + a.w);
        s2 += (a.x * a.x + a.y * a.y) + (a.z * a.z + a.w * a.w);
    }
#pragma unroll
    for (int o = 1; o < 64; o <<= 1) { s += __shfl_xor(s, o); s2 += __shfl_xor(s2, o); }
    float mu = s * (1.f / 768.f);
    float var = s2 * (1.f / 768.f) - mu * mu;
    float rs = rsqrtf(var + 1e-5f);
    const float4* xr = xinf ? (const float4*)(xinf + (size_t)row * DIM_) : nullptr;
    const ushort4* xb = xinb ? (const ushort4*)(xinb + (size_t)row * DIM_) : nullptr;
    const float4* g4 = (const float4*)g;
    const float4* b4 = (const float4*)be;
    float4* of = outf ? (float4*)(outf + (size_t)row * DIM_) : nullptr;
#pragma unroll
    for (int i = 0; i < 3; i++) {
        int c = i * 64 + lane;
        float4 gg = g4[c], bb = b4[c];
        float4 xx;
        if (xr) xx = xr[c];
        else {
            ushort4 u = xb[c];
            xx = { bf2f(u.x), bf2f(u.y), bf2f(u.z), bf2f(u.w) };
        }
        float4 o;
        o.x = xx.x + (v[i].x - mu) * rs * gg.x + bb.x;
        o.y = xx.y + (v[i].y - mu) * rs * gg.y + bb.y;
        o.z = xx.z + (v[i].z - mu) * rs * gg.z + bb.z;
        o.w = xx.w + (v[i].w - mu) * rs * gg.w + bb.w;
        if (of) of[c] = o;
        if (outbf) {
            ushort4 ob;
            ob.x = f2bf(o.x); ob.y = f2bf(o.y); ob.z = f2bf(o.z); ob.w = f2bf(o.w);
            ((ushort4*)(outbf + (size_t)row * DIM_))[c] = ob;
        }
    }
}

// ---------------- launch ----------------
extern "C" void kernel_launch(void* const* d_in, const int* in_sizes, int n_in,
                              void* d_out, int out_size, void* d_ws, size_t ws_size,
                              hipStream_t stream)
{
    const float* x    = (const float*)d_in[0];
    const float* Wqkv = (const float*)d_in[1];
    const float* bqkv = (const float*)d_in[2];
    const float* Wproj= (const float*)d_in[3];
    const float* bproj= (const float*)d_in[4];
    const float* W1   = (const float*)d_in[5];
    const float* b1   = (const float*)d_in[6];
    const float* W2   = (const float*)d_in[7];
    const float* b2   = (const float*)d_in[8];
    const float* g1   = (const float*)d_in[9];
    const float* be1  = (const float*)d_in[10];
    const float* g2   = (const float*)d_in[11];
    const float* be2  = (const float*)d_in[12];
    float* out = (float*)d_out;

    char* ws = (char*)d_ws;
    size_t off = 0;
    auto alloc = [&](size_t bytes) -> void* {
        void* p = ws + off;
        off += (bytes + 255) & ~(size_t)255;
        return p;
    };
    // weights first (live all along)
    ushort* wqkvT  = (ushort*)alloc((size_t)2304 * 768 * 2);
    ushort* wprojT = (ushort*)alloc((size_t)768 * 768 * 2);
    ushort* w1T    = (ushort*)alloc((size_t)3072 * 768 * 2);
    ushort* w2T    = (ushort*)alloc((size_t)768 * 3072 * 2);
    // BLOCK_A: xbf/qb/kb/vb (dead after attn/v_transpose) — aliased by hbf.
    ushort* xbf    = (ushort*)alloc((size_t)ROWS_ * DIM_ * 2);
    ushort* qb     = (ushort*)alloc((size_t)ROWS_ * DIM_ * 2);
    ushort* kb     = (ushort*)alloc((size_t)ROWS_ * DIM_ * 2);
    ushort* vb     = (ushort*)alloc((size_t)ROWS_ * DIM_ * 2);  // row-major V
    ushort* hbf    = xbf;  // alias: 4*ROWS*DIM*2 == ROWS*HID*2
    ushort* vT     = (ushort*)alloc((size_t)ROWS_ * DIM_ * 2);  // transposed V (outside alias)
    ushort* aobf   = (ushort*)alloc((size_t)ROWS_ * DIM_ * 2);
    ushort* projp  = (ushort*)alloc((size_t)2 * ROWS_ * DIM_ * 2); // bf16 split-K partials
    ushort* x1bf   = (ushort*)alloc((size_t)ROWS_ * DIM_ * 2);
    ushort* projp1 = projp + (size_t)ROWS_ * DIM_;

    // prep
    cast_bf16_kernel<<<(ROWS_ * DIM_ / 4 + 255) / 256, 256, 0, stream>>>(x, xbf, ROWS_ * DIM_ / 4);
    transpose_cast_qkv_kernel<<<dim3(2304 / 32, 768 / 32), dim3(32, 8), 0, stream>>>(Wqkv, wqkvT);
    transpose_cast_kernel<<<dim3(768 / 32, 768 / 32), dim3(32, 8), 0, stream>>>(Wproj, wprojT, 768, 768);
    transpose_cast_kernel<<<dim3(3072 / 32, 768 / 32), dim3(32, 8), 0, stream>>>(W1, w1T, 768, 3072);
    transpose_cast_kernel<<<dim3(768 / 32, 3072 / 32), dim3(32, 8), 0, stream>>>(W2, w2T, 3072, 768);

    // qkv = x @ Wqkv(perm) + bqkv -> q/k/v all row-major (1152 blocks, nx=18)
    gemm_bt<EPI_QKV><<<1152, 256, 0, stream>>>(
        xbf, wqkvT, bqkv, nullptr, qb, kb, vb, ROWS_, 2304, 768, 18, 1, 768);

    // V transpose: vb -> vT (coalesced LDS-tile transpose per head)
    v_transpose_kernel<<<dim3(2, 32, 96), dim3(32, 8), 0, stream>>>(vb, vT);

    // attention -> aobf (768 blocks, XCD-local heads)
    attn_kernel<<<768, 256, 0, stream>>>(qb, kb, vT, aobf);

    // proj: split-K x2 (768 blocks, nx=6, Ksl=384) -> bf16 partials
    gemm_bt<EPI_PART><<<768, 256, 0, stream>>>(
        aobf, wprojT, bproj, projp, nullptr, nullptr, nullptr, ROWS_, 768, 768, 6, 2, 384);

    // x1 = x + LN(projp0 + projp1) -> x1bf only
    ln_residual_kernel<<<ROWS_ / 4, 256, 0, stream>>>(
        x, nullptr, projp, projp1, g1, be1, nullptr, x1bf, ROWS_);

    // h = gelu(x1 @ W1 + b1)  (1536 blocks, nx=24) — hbf aliases dead BLOCK_A
    gemm_bt<EPI_GELU><<<1536, 256, 0, stream>>>(
        x1bf, w1T, b1, hbf, nullptr, nullptr, nullptr, ROWS_, 3072, 768, 24, 1, 768);

    // mlp = h @ W2 + b2: split-K x2 (768 blocks, nx=6, Ksl=1536)
    gemm_bt<EPI_PART><<<768, 256, 0, stream>>>(
        hbf, w2T, b2, projp, nullptr, nullptr, nullptr, ROWS_, 768, 3072, 6, 2, 1536);

    // out = x1 + LN(mlp0 + mlp1), residual from bf16 x1
    ln_residual_kernel<<<ROWS_ / 4, 256, 0, stream>>>(
        nullptr, x1bf, projp, projp1, g2, be2, out, nullptr, ROWS_);
}